// Round 1
// baseline (464.708 us; speedup 1.0000x reference)
//
#include <hip/hip_runtime.h>
#include <cstddef>

// Problem constants (b=2,h=16,L=4096,d=16,dv=64, chunk=256)
#define BH    32
#define LSEQ  4096
#define D     16
#define DV    64
#define CS    256
#define NC    16          // chunks per (b,h)
#define NR    273         // feature dim: 1 + 16 + 256
#define DVZ   65          // dv + 1 (z column)
#define STATE (NR * DVZ)  // 17745 floats per (bh, chunk)

// -------------------- Pass A: per-chunk state  KV_c = sum_j chi(k_j) (x) v'_j
// grid = BH*NC blocks, 320 threads (5 waves).
// wave 0: rows 0..16 (const + linear), waves 1..4: quad rows for d in [4(w-1),4w)
// threads 0..255 additionally compute the z-column (f=64): sum_j chi_r(k_j)
__global__ __launch_bounds__(320) void pass_a_kernel(
    const float* __restrict__ k, const float* __restrict__ v,
    float* __restrict__ ws) {
  const int blk = blockIdx.x;
  const int bh = blk / NC;
  const int c  = blk % NC;
  const float* kc = k + ((size_t)bh * LSEQ + (size_t)c * CS) * D;
  const float* vc = v + ((size_t)bh * LSEQ + (size_t)c * CS) * DV;
  float* out = ws + (size_t)blk * STATE;
  const int t = threadIdx.x;
  const int wave = t >> 6;
  const int lane = t & 63;   // f column 0..63

  if (wave == 0) {
    float acc[17];
#pragma unroll
    for (int i = 0; i < 17; ++i) acc[i] = 0.f;
    for (int j = 0; j < CS; ++j) {
      float vj = vc[j * DV + lane];
      const float4* kr = (const float4*)(kc + j * D);
      float4 k0 = kr[0], k1 = kr[1], k2 = kr[2], k3 = kr[3];
      float ke[16] = {k0.x,k0.y,k0.z,k0.w, k1.x,k1.y,k1.z,k1.w,
                      k2.x,k2.y,k2.z,k2.w, k3.x,k3.y,k3.z,k3.w};
      acc[0] += vj;
#pragma unroll
      for (int dd = 0; dd < 16; ++dd) acc[1 + dd] += ke[dd] * vj;
    }
#pragma unroll
    for (int r = 0; r < 17; ++r) out[(size_t)r * DVZ + lane] = acc[r];
  } else {
    const int d0 = (wave - 1) * 4;
    float acc[64];
#pragma unroll
    for (int i = 0; i < 64; ++i) acc[i] = 0.f;
    for (int j = 0; j < CS; ++j) {
      float vj = vc[j * DV + lane];
      const float4* kr = (const float4*)(kc + j * D);
      float4 k0 = kr[0], k1 = kr[1], k2 = kr[2], k3 = kr[3];
      float ke[16] = {k0.x,k0.y,k0.z,k0.w, k1.x,k1.y,k1.z,k1.w,
                      k2.x,k2.y,k2.z,k2.w, k3.x,k3.y,k3.z,k3.w};
      float4 kd = *(const float4*)(kc + j * D + d0);  // 16B aligned (d0 in {0,4,8,12})
      float kdv0 = kd.x * vj, kdv1 = kd.y * vj, kdv2 = kd.z * vj, kdv3 = kd.w * vj;
#pragma unroll
      for (int ee = 0; ee < 16; ++ee) {
        acc[0*16+ee] += kdv0 * ke[ee];
        acc[1*16+ee] += kdv1 * ke[ee];
        acc[2*16+ee] += kdv2 * ke[ee];
        acc[3*16+ee] += kdv3 * ke[ee];
      }
    }
#pragma unroll
    for (int dd = 0; dd < 4; ++dd)
#pragma unroll
      for (int ee = 0; ee < 16; ++ee)
        out[(size_t)(17 + (d0 + dd) * 16 + ee) * DVZ + lane] = acc[dd*16+ee];
  }

  // z-column (f = 64): chi feature sums. Runtime d,e indices hit global/L1, not regs.
  if (t < 256) {
#pragma unroll
    for (int pass = 0; pass < 2; ++pass) {
      int r = t + pass * 256;  // covers 0..255 and 256..272
      if (r < NR) {
        float s;
        if (r == 0) {
          s = (float)CS;
        } else if (r < 17) {
          int dd = r - 1;
          s = 0.f;
          for (int j = 0; j < CS; ++j) s += kc[j * D + dd];
        } else {
          int idx = r - 17, dd = idx >> 4, ee = idx & 15;
          s = 0.f;
          for (int j = 0; j < CS; ++j) s += kc[j * D + dd] * kc[j * D + ee];
        }
        out[(size_t)r * DVZ + 64] = s;
      }
    }
  }
}

// -------------------- Pass B: in-place exclusive prefix over chunk axis
__global__ __launch_bounds__(256) void pass_b_kernel(float* __restrict__ ws) {
  const int idx = blockIdx.x * 256 + threadIdx.x;
  const int TOT = BH * STATE;
  if (idx >= TOT) return;
  const int bh = idx / STATE;
  const int rf = idx - bh * STATE;
  float* p = ws + (size_t)bh * NC * STATE + rf;
  float run = 0.f;
#pragma unroll
  for (int c = 0; c < NC; ++c) {
    float val = p[(size_t)c * STATE];
    p[(size_t)c * STATE] = run;
    run += val;
  }
}

// -------------------- Pass C: output = (psi(q)·S + intra causal phi attn) / z
// grid = BH*NC blocks, 256 threads (1 thread = 1 query row).
#define TR 91  // state tile rows; 3*91 = 273
__global__ __launch_bounds__(256) void pass_c_kernel(
    const float* __restrict__ q, const float* __restrict__ k,
    const float* __restrict__ v, const float* __restrict__ ws,
    float* __restrict__ out) {
  __shared__ float smem[TR * DVZ];   // 5915 floats; also reused for K/V tiles (5120)
  __shared__ float qs[CS][17];       // stride 17: coprime with 32 banks -> conflict-free
  const int blk = blockIdx.x;
  const int bh = blk / NC;
  const int c  = blk % NC;
  const size_t base = (size_t)bh * LSEQ + (size_t)c * CS;
  const float* qc = q + base * D;
  const float* kc = k + base * D;
  const float* vc = v + base * DV;
  const float* S  = ws + (size_t)blk * STATE;
  float* oc = out + base * DV;
  const int t = threadIdx.x;

  // load + scale q row (d^-0.5 = 0.25)
  float qr[16];
  {
    const float4* qp = (const float4*)(qc + (size_t)t * D);
    float4 a = qp[0], b = qp[1], cc = qp[2], d4 = qp[3];
    qr[0]=a.x*0.25f;  qr[1]=a.y*0.25f;  qr[2]=a.z*0.25f;  qr[3]=a.w*0.25f;
    qr[4]=b.x*0.25f;  qr[5]=b.y*0.25f;  qr[6]=b.z*0.25f;  qr[7]=b.w*0.25f;
    qr[8]=cc.x*0.25f; qr[9]=cc.y*0.25f; qr[10]=cc.z*0.25f;qr[11]=cc.w*0.25f;
    qr[12]=d4.x*0.25f;qr[13]=d4.y*0.25f;qr[14]=d4.z*0.25f;qr[15]=d4.w*0.25f;
  }
#pragma unroll
  for (int i = 0; i < 16; ++i) qs[t][i] = qr[i];  // own row only -> no barrier needed

  float acc[DV];
#pragma unroll
  for (int f = 0; f < DV; ++f) acc[f] = 0.f;
  float z = 0.f;

  // ---- inter-chunk state apply: acc += psi(q) · S
  for (int tile = 0; tile < 3; ++tile) {
    __syncthreads();
    const int r0 = tile * TR;
    for (int i = t; i < TR * DVZ; i += 256) smem[i] = S[(size_t)r0 * DVZ + i];
    __syncthreads();
    for (int rl = 0; rl < TR; ++rl) {
      const int r = r0 + rl;
      float psi;
      if (r == 0)       psi = 1.f;
      else if (r < 17)  psi = qs[t][r - 1];
      else { int idx = r - 17; psi = 0.5f * qs[t][idx >> 4] * qs[t][idx & 15]; }
      const float* row = smem + rl * DVZ;  // broadcast across lanes
#pragma unroll
      for (int f = 0; f < DV; ++f) acc[f] += psi * row[f];
      z += psi * row[DV];
    }
  }

  // ---- intra-chunk causal phi-attention, j-tiles of 64
  for (int jt = 0; jt < 4; ++jt) {
    __syncthreads();
    const float* kt = kc + (size_t)jt * 64 * D;
    const float* vt = vc + (size_t)jt * 64 * DV;
    for (int i = t; i < 64 * D;  i += 256) smem[i] = kt[i];
    for (int i = t; i < 64 * DV; i += 256) smem[1024 + i] = vt[i];
    __syncthreads();
    int jend = t - jt * 64 + 1;
    if (jend > 64) jend = 64;
    for (int jl = 0; jl < jend; ++jl) {
      const float* kj = smem + jl * D;
      float s = 0.f;
#pragma unroll
      for (int dd = 0; dd < 16; ++dd) s += qr[dd] * kj[dd];
      float phi = 1.f + s + 0.5f * s * s;
      const float* vj = smem + 1024 + jl * DV;
#pragma unroll
      for (int f = 0; f < DV; ++f) acc[f] += phi * vj[f];
      z += phi;
    }
  }

  const float inv = 1.f / (z + 1e-6f);
  float4* op = (float4*)(oc + (size_t)t * DV);
#pragma unroll
  for (int f4 = 0; f4 < 16; ++f4) {
    float4 o4 = {acc[f4*4+0]*inv, acc[f4*4+1]*inv, acc[f4*4+2]*inv, acc[f4*4+3]*inv};
    op[f4] = o4;
  }
}

extern "C" void kernel_launch(void* const* d_in, const int* in_sizes, int n_in,
                              void* d_out, int out_size, void* d_ws, size_t ws_size,
                              hipStream_t stream) {
  (void)in_sizes; (void)n_in; (void)out_size; (void)ws_size;
  const float* q = (const float*)d_in[0];
  const float* k = (const float*)d_in[1];
  const float* v = (const float*)d_in[2];
  float* out = (float*)d_out;
  float* ws  = (float*)d_ws;   // needs 512 * 17745 * 4 B ~= 34.7 MiB

  pass_a_kernel<<<BH * NC, 320, 0, stream>>>(k, v, ws);
  const int tot = BH * STATE;
  pass_b_kernel<<<(tot + 255) / 256, 256, 0, stream>>>(ws);
  pass_c_kernel<<<BH * NC, 256, 0, stream>>>(q, k, v, ws, out);
}

// Round 2
// 330.246 us; speedup vs baseline: 1.4072x; 1.4072x over previous
//
#include <hip/hip_runtime.h>
#include <cstddef>

// Problem constants (b=2,h=16,L=4096,d=16,dv=64, chunk=256)
#define BH    32
#define LSEQ  4096
#define D     16
#define DV    64
#define CS    256
#define NC    16           // chunks per (b,h)
#define NR    273          // feature dim: 1 + 16 + 256
#define DVZ   65           // dv + 1 (z column)
#define SROW  68           // padded state row stride (17 float4s, 16B aligned)
#define STATE_P (NR * SROW)  // 18564 floats per (bh, chunk) ~ 38 MB total ws

// -------------------- Pass A: per-chunk state  KV_c = sum_j chi(k_j) (x) v'_j
// grid = BH*NC blocks, 320 threads (5 waves).
__global__ __launch_bounds__(320) void pass_a_kernel(
    const float* __restrict__ k, const float* __restrict__ v,
    float* __restrict__ ws) {
  const int blk = blockIdx.x;
  const int bh = blk / NC;
  const int c  = blk % NC;
  const float* kc = k + ((size_t)bh * LSEQ + (size_t)c * CS) * D;
  const float* vc = v + ((size_t)bh * LSEQ + (size_t)c * CS) * DV;
  float* out = ws + (size_t)blk * STATE_P;
  const int t = threadIdx.x;
  const int wave = t >> 6;
  const int lane = t & 63;   // f column 0..63

  if (wave == 0) {
    float acc[17];
#pragma unroll
    for (int i = 0; i < 17; ++i) acc[i] = 0.f;
    for (int j = 0; j < CS; ++j) {
      float vj = vc[j * DV + lane];
      const float4* kr = (const float4*)(kc + j * D);
      float4 k0 = kr[0], k1 = kr[1], k2 = kr[2], k3 = kr[3];
      float ke[16] = {k0.x,k0.y,k0.z,k0.w, k1.x,k1.y,k1.z,k1.w,
                      k2.x,k2.y,k2.z,k2.w, k3.x,k3.y,k3.z,k3.w};
      acc[0] += vj;
#pragma unroll
      for (int dd = 0; dd < 16; ++dd) acc[1 + dd] += ke[dd] * vj;
    }
#pragma unroll
    for (int r = 0; r < 17; ++r) out[(size_t)r * SROW + lane] = acc[r];
  } else {
    const int d0 = (wave - 1) * 4;
    float acc[64];
#pragma unroll
    for (int i = 0; i < 64; ++i) acc[i] = 0.f;
    for (int j = 0; j < CS; ++j) {
      float vj = vc[j * DV + lane];
      const float4* kr = (const float4*)(kc + j * D);
      float4 k0 = kr[0], k1 = kr[1], k2 = kr[2], k3 = kr[3];
      float ke[16] = {k0.x,k0.y,k0.z,k0.w, k1.x,k1.y,k1.z,k1.w,
                      k2.x,k2.y,k2.z,k2.w, k3.x,k3.y,k3.z,k3.w};
      float4 kd = *(const float4*)(kc + j * D + d0);
      float kdv0 = kd.x * vj, kdv1 = kd.y * vj, kdv2 = kd.z * vj, kdv3 = kd.w * vj;
#pragma unroll
      for (int ee = 0; ee < 16; ++ee) {
        acc[0*16+ee] += kdv0 * ke[ee];
        acc[1*16+ee] += kdv1 * ke[ee];
        acc[2*16+ee] += kdv2 * ke[ee];
        acc[3*16+ee] += kdv3 * ke[ee];
      }
    }
#pragma unroll
    for (int dd = 0; dd < 4; ++dd)
#pragma unroll
      for (int ee = 0; ee < 16; ++ee)
        out[(size_t)(17 + (d0 + dd) * 16 + ee) * SROW + lane] = acc[dd*16+ee];
  }

  // z-column (col 64): chi feature sums
  if (t < 256) {
#pragma unroll
    for (int pass = 0; pass < 2; ++pass) {
      int r = t + pass * 256;
      if (r < NR) {
        float s;
        if (r == 0) {
          s = (float)CS;
        } else if (r < 17) {
          int dd = r - 1;
          s = 0.f;
          for (int j = 0; j < CS; ++j) s += kc[j * D + dd];
        } else {
          int idx = r - 17, dd = idx >> 4, ee = idx & 15;
          s = 0.f;
          for (int j = 0; j < CS; ++j) s += kc[j * D + dd] * kc[j * D + ee];
        }
        out[(size_t)r * SROW + 64] = s;
      }
    }
  }
}

// -------------------- Pass B: in-place exclusive prefix over chunk axis
__global__ __launch_bounds__(256) void pass_b_kernel(float* __restrict__ ws) {
  const int idx = blockIdx.x * 256 + threadIdx.x;
  const int TOT = BH * STATE_P;
  if (idx >= TOT) return;
  const int bh = idx / STATE_P;
  const int rf = idx - bh * STATE_P;
  float* p = ws + (size_t)bh * NC * STATE_P + rf;
  float run = 0.f;
#pragma unroll
  for (int c = 0; c < NC; ++c) {
    float val = p[(size_t)c * STATE_P];
    p[(size_t)c * STATE_P] = run;
    run += val;
  }
}

// -------------------- Pass C v2: register-tiled
// grid = BH*NC blocks (one chunk each), 512 threads (8 waves).
// thread t: fg = t&3 (16 f-cols starting fg*16), qg = t>>2 (queries 2qg, 2qg+1)
// Each thread: acc[2 queries][16 f] in regs + redundant z per query (uniform
// across fg -> no cross-thread reduction needed).
__global__ __launch_bounds__(512, 4) void pass_c_kernel(
    const float* __restrict__ q, const float* __restrict__ k,
    const float* __restrict__ v, const float* __restrict__ ws,
    float* __restrict__ out) {
  __shared__ __align__(16) float st[64 * SROW];     // 17408 B: S tile / V tile
  __shared__ __align__(16) float qs[CS * 17];       // 17408 B: q rows, stride 17
  __shared__ __align__(16) float ktile[64 * D];     // 4096 B
  const int blk = blockIdx.x;
  const int bh = blk / NC;
  const int c  = blk % NC;
  const size_t base = (size_t)bh * LSEQ + (size_t)c * CS;
  const float* qc = q + base * D;
  const float* kc = k + base * D;
  const float* vc = v + base * DV;
  const float* Sg = ws + (size_t)blk * STATE_P;
  float* oc = out + base * DV;

  const int t  = threadIdx.x;
  const int fg = t & 3;
  const int qg = t >> 2;
  const int q0 = qg * 2;
  const int q1 = q0 + 1;

  // load + scale both q rows (d^-0.5 = 0.25) into registers
  float qa0[16], qa1[16];
  {
    const float4* qp0 = (const float4*)(qc + (size_t)q0 * D);
    const float4* qp1 = (const float4*)(qc + (size_t)q1 * D);
#pragma unroll
    for (int m = 0; m < 4; ++m) {
      float4 a = qp0[m], b = qp1[m];
      qa0[m*4+0]=a.x*0.25f; qa0[m*4+1]=a.y*0.25f; qa0[m*4+2]=a.z*0.25f; qa0[m*4+3]=a.w*0.25f;
      qa1[m*4+0]=b.x*0.25f; qa1[m*4+1]=b.y*0.25f; qa1[m*4+2]=b.z*0.25f; qa1[m*4+3]=b.w*0.25f;
    }
  }
  if (fg == 0) {
#pragma unroll
    for (int dd = 0; dd < 16; ++dd) {
      qs[q0 * 17 + dd] = qa0[dd];
      qs[q1 * 17 + dd] = qa1[dd];
    }
  }

  float4 acc0[4], acc1[4];
#pragma unroll
  for (int m = 0; m < 4; ++m) {
    acc0[m] = make_float4(0.f, 0.f, 0.f, 0.f);
    acc1[m] = make_float4(0.f, 0.f, 0.f, 0.f);
  }
  float z0 = 0.f, z1 = 0.f;

#define FMA4(ACC, P, X) do { \
    (ACC).x = fmaf((P), (X).x, (ACC).x); \
    (ACC).y = fmaf((P), (X).y, (ACC).y); \
    (ACC).z = fmaf((P), (X).z, (ACC).z); \
    (ACC).w = fmaf((P), (X).w, (ACC).w); } while (0)

  // ---- inter stage A: rows 0..16 (const + linear)
  __syncthreads();   // qs visible; st free
  {
    const float4* src = (const float4*)Sg;
    for (int i4 = t; i4 < 17 * (SROW/4); i4 += 512) ((float4*)st)[i4] = src[i4];
  }
  __syncthreads();
  {
    // r = 0: psi = 1
    const float4* sr = (const float4*)(st + fg * 16);
#pragma unroll
    for (int m = 0; m < 4; ++m) {
      float4 s4 = sr[m];
      FMA4(acc0[m], 1.f, s4);
      FMA4(acc1[m], 1.f, s4);
    }
    float sz = st[64];
    z0 += sz; z1 += sz;
    // r = 1..16: psi_i = qa_i[ee]
#pragma unroll
    for (int ee = 0; ee < 16; ++ee) {
      const int rl = 1 + ee;
      const float4* s = (const float4*)(st + rl * SROW + fg * 16);
      float4 A = s[0], B = s[1], Cc = s[2], Dd = s[3];
      float p0 = qa0[ee], p1 = qa1[ee];
      FMA4(acc0[0], p0, A); FMA4(acc0[1], p0, B); FMA4(acc0[2], p0, Cc); FMA4(acc0[3], p0, Dd);
      FMA4(acc1[0], p1, A); FMA4(acc1[1], p1, B); FMA4(acc1[2], p1, Cc); FMA4(acc1[3], p1, Dd);
      float z4 = st[rl * SROW + 64];
      z0 = fmaf(p0, z4, z0); z1 = fmaf(p1, z4, z1);
    }
  }

  // ---- inter quad stages: rows 17 + dd*16 + ee, staged 64 rows at a time
  for (int s = 0; s < 4; ++s) {
    __syncthreads();
    {
      const float4* src = (const float4*)(Sg + (size_t)(17 + 64 * s) * SROW);
      for (int i4 = t; i4 < 64 * (SROW/4); i4 += 512) ((float4*)st)[i4] = src[i4];
    }
    __syncthreads();
    for (int ddp = 0; ddp < 4; ++ddp) {
      const int dd = s * 4 + ddp;
      float qd0 = 0.5f * qs[q0 * 17 + dd];
      float qd1 = 0.5f * qs[q1 * 17 + dd];
#pragma unroll
      for (int ee = 0; ee < 16; ++ee) {
        const int rl = ddp * 16 + ee;
        const float4* sr = (const float4*)(st + rl * SROW + fg * 16);
        float4 A = sr[0], B = sr[1], Cc = sr[2], Dd = sr[3];
        float p0 = qd0 * qa0[ee];
        float p1 = qd1 * qa1[ee];
        FMA4(acc0[0], p0, A); FMA4(acc0[1], p0, B); FMA4(acc0[2], p0, Cc); FMA4(acc0[3], p0, Dd);
        FMA4(acc1[0], p1, A); FMA4(acc1[1], p1, B); FMA4(acc1[2], p1, Cc); FMA4(acc1[3], p1, Dd);
        float z4 = st[rl * SROW + 64];
        z0 = fmaf(p0, z4, z0); z1 = fmaf(p1, z4, z1);
      }
    }
  }

  // ---- intra-chunk causal phi-attention, j-tiles of 64 (V tile reuses st)
  for (int jt = 0; jt < 4; ++jt) {
    __syncthreads();
    {
      const float4* ksrc = (const float4*)(kc + (size_t)jt * 64 * D);
      if (t < 256) ((float4*)ktile)[t] = ksrc[t];
      const float4* vsrc = (const float4*)(vc + (size_t)jt * 64 * DV);
      int idx = t, row = idx >> 4, c4 = idx & 15;
      *(float4*)(st + row * SROW + c4 * 4) = vsrc[idx];
      idx = t + 512; row = idx >> 4; c4 = idx & 15;
      *(float4*)(st + row * SROW + c4 * 4) = vsrc[idx];
    }
    __syncthreads();
    const int jbase = jt * 64;
    int jend = q1 - jbase + 1;
    if (jend > 64) jend = 64;
    for (int jl = 0; jl < jend; ++jl) {
      const float4* kr = (const float4*)(ktile + jl * D);
      float4 k0 = kr[0], k1 = kr[1], k2 = kr[2], k3 = kr[3];
      float kf[16] = {k0.x,k0.y,k0.z,k0.w, k1.x,k1.y,k1.z,k1.w,
                      k2.x,k2.y,k2.z,k2.w, k3.x,k3.y,k3.z,k3.w};
      float s0 = 0.f, s1 = 0.f;
#pragma unroll
      for (int dd = 0; dd < 16; ++dd) {
        s0 = fmaf(qa0[dd], kf[dd], s0);
        s1 = fmaf(qa1[dd], kf[dd], s1);
      }
      float p0 = fmaf(0.5f * s0, s0, s0) + 1.0f;
      float p1 = fmaf(0.5f * s1, s1, s1) + 1.0f;
      p0 = (jbase + jl <= q0) ? p0 : 0.f;   // jl < jend already guarantees <= q1
      const float4* vr = (const float4*)(st + jl * SROW + fg * 16);
      float4 A = vr[0], B = vr[1], Cc = vr[2], Dd = vr[3];
      FMA4(acc0[0], p0, A); FMA4(acc0[1], p0, B); FMA4(acc0[2], p0, Cc); FMA4(acc0[3], p0, Dd);
      FMA4(acc1[0], p1, A); FMA4(acc1[1], p1, B); FMA4(acc1[2], p1, Cc); FMA4(acc1[3], p1, Dd);
      z0 += p0; z1 += p1;
    }
  }

  // ---- normalize + store (z identical across the 4 fg threads of a query)
  const float inv0 = 1.0f / (z0 + 1e-6f);
  const float inv1 = 1.0f / (z1 + 1e-6f);
  float4* o0 = (float4*)(oc + (size_t)q0 * DV + fg * 16);
  float4* o1 = (float4*)(oc + (size_t)q1 * DV + fg * 16);
#pragma unroll
  for (int m = 0; m < 4; ++m) {
    float4 a = acc0[m], b = acc1[m];
    o0[m] = make_float4(a.x*inv0, a.y*inv0, a.z*inv0, a.w*inv0);
    o1[m] = make_float4(b.x*inv1, b.y*inv1, b.z*inv1, b.w*inv1);
  }
#undef FMA4
}

extern "C" void kernel_launch(void* const* d_in, const int* in_sizes, int n_in,
                              void* d_out, int out_size, void* d_ws, size_t ws_size,
                              hipStream_t stream) {
  (void)in_sizes; (void)n_in; (void)out_size; (void)ws_size;
  const float* q = (const float*)d_in[0];
  const float* k = (const float*)d_in[1];
  const float* v = (const float*)d_in[2];
  float* out = (float*)d_out;
  float* ws  = (float*)d_ws;   // needs 512 * 18564 * 4 B ~= 38.0 MiB

  pass_a_kernel<<<BH * NC, 320, 0, stream>>>(k, v, ws);
  const int tot = BH * STATE_P;
  pass_b_kernel<<<(tot + 255) / 256, 256, 0, stream>>>(ws);
  pass_c_kernel<<<BH * NC, 512, 0, stream>>>(q, k, v, ws, out);
}

// Round 3
// 162.632 us; speedup vs baseline: 2.8574x; 2.0306x over previous
//
#include <hip/hip_runtime.h>
#include <cstddef>

// Problem: b=2,h=16,L=4096,d=16,dv=64, chunk=256. Second-order linear attn.
#define BH    32
#define LSEQ  4096
#define D     16
#define DV    64
#define CS    256
#define NC    16
#define NF    160     // padded feature dim (153 real: 1 const + 16 lin + 120 pair + 16 diag)
#define NZ    65      // 64 v cols + z col
#define KSTEPS 5      // NF/32

typedef short short8 __attribute__((ext_vector_type(8)));
typedef float f32x4 __attribute__((ext_vector_type(4)));

// ws layout (bytes): total ~30.4 MiB
#define OFF_KBF 0u                                   // [BH][LSEQ][16] bf16  (4 MiB)
#define OFF_VT  (4u*1024u*1024u)                     // [BH][NZ][LSEQ] bf16  (17.04 MB; row 64 = ones)
#define OFF_ST  (OFF_VT + (unsigned)(BH*NZ*LSEQ*2)) // [BH][NC][NZ][NF] bf16 (10.65 MB)

__device__ __forceinline__ unsigned f2bf(float x) {
  unsigned u = __float_as_uint(x);
  return (u + 0x7FFFu + ((u >> 16) & 1u)) >> 16;   // RNE; inputs always finite
}
__device__ __forceinline__ short8 zero8() {
  short8 z = {0,0,0,0,0,0,0,0};
  return z;
}

// feature table: d | (e<<8) | (psi_half?1<<16:0).  qx/kx rows have [16]=1, [17]=0.
__device__ __forceinline__ unsigned feat_tbl(int f) {
  if (f == 0)  return 16u | (16u << 8);                       // const: 1*1
  if (f <= 16) return (unsigned)(f - 1) | (16u << 8);         // linear: x_d * 1
  if (f < 137) {                                              // pairs d<e
    int p = f - 17, off = 0;
    for (int d = 0; d < 15; ++d) {
      int cnt = 15 - d;
      if (p < off + cnt) return (unsigned)d | ((unsigned)(d + 1 + p - off) << 8);
      off += cnt;
    }
  }
  if (f < 153) {                                              // diag: psi=0.5*q_d^2, chi=k_d^2
    int d = f - 137;
    return (unsigned)d | ((unsigned)d << 8) | (1u << 16);
  }
  return 17u | (17u << 8);                                    // pad: 0*0
}

// ---------------- pass0_k: k fp32 -> bf16 rows [bh][j][16]
__global__ __launch_bounds__(256) void pass0_k(const float* __restrict__ k,
                                               unsigned* __restrict__ kbf) {
  int idx = blockIdx.x * 256 + threadIdx.x;   // 1,048,576 pairs
  float2 v2 = ((const float2*)k)[idx];
  kbf[idx] = f2bf(v2.x) | (f2bf(v2.y) << 16);
}

// ---------------- pass0_v: build V^T bf16 [bh][f][j] + ones row f=64
__global__ __launch_bounds__(256) void pass0_v(const float* __restrict__ v,
                                               unsigned* __restrict__ vt_u32) {
  __shared__ float tile[64][129];
  int blk = blockIdx.x, bh = blk >> 4, jb = (blk & 15) * 256;
  const float* vb = v + ((size_t)bh * LSEQ + jb) * DV;
  int t = threadIdx.x;
  for (int half = 0; half < 2; ++half) {
    __syncthreads();
    for (int i = t; i < 128 * 64; i += 256) {       // read rows (coalesced), transpose to LDS
      int j = i >> 6, f = i & 63;
      tile[f][j] = vb[(half * 128 + j) * DV + f];
    }
    __syncthreads();
    for (int o = t; o < 64 * 64; o += 256) {        // write V_T rows (coalesced u32)
      int f = o >> 6, jp = (o & 63) * 2;
      unsigned p = f2bf(tile[f][jp]) | (f2bf(tile[f][jp + 1]) << 16);
      vt_u32[(size_t)(bh * NZ + f) * (LSEQ / 2) + (jb + half * 128 + jp) / 2] = p;
    }
  }
  if (t < 128) {  // ones row (f = 64): bf16(1.0) = 0x3F80
    vt_u32[(size_t)(bh * NZ + 64) * (LSEQ / 2) + jb / 2 + t] = 0x3F803F80u;
  }
}

// ---------------- pass_a: per-chunk state S_c[feat][col] = sum_j chi(k_j) v'_j  (MFMA)
// 512 blocks (one chunk), 320 threads = 5 waves; wave w -> feat M-tiles {2w,2w+1}.
// Epilogue: LDS transpose -> ST bf16 [bh][c][col][feat].
__global__ __launch_bounds__(320) void pass_a(const float* __restrict__ k,
                                              const unsigned short* __restrict__ vt,
                                              unsigned short* __restrict__ st) {
  __shared__ float kx[32][18];
  __shared__ unsigned tbl[NF];
  __shared__ float tile[NF][67];
  int blk = blockIdx.x, bh = blk >> 4, c = blk & 15;
  const float* kc = k + ((size_t)bh * LSEQ + c * CS) * D;
  const unsigned short* vtb = vt + (size_t)bh * NZ * LSEQ + (size_t)c * CS;
  int t = threadIdx.x, w = t >> 6, lane = t & 63, quad = lane >> 4, n16 = lane & 15;
  if (t < NF) tbl[t] = feat_tbl(t);
  f32x4 acc[2][5];
#pragma unroll
  for (int mm = 0; mm < 2; ++mm)
#pragma unroll
    for (int nt = 0; nt < 5; ++nt) acc[mm][nt] = (f32x4){0.f, 0.f, 0.f, 0.f};

  for (int jt = 0; jt < 8; ++jt) {
    __syncthreads();
    for (int i = t; i < 512; i += 320) {
      int j = i >> 4, dd = i & 15;
      kx[j][dd] = kc[(jt * 32 + j) * D + dd];
    }
    if (t < 32) { kx[t][16] = 1.f; kx[t][17] = 0.f; }
    __syncthreads();
    // chi A-fragments: A[m=feat][k=j]
    short8 afr[2];
#pragma unroll
    for (int mm = 0; mm < 2; ++mm) {
      int feat = (w * 2 + mm) * 16 + n16;
      unsigned tv = tbl[feat];
      int d = tv & 255, e = (tv >> 8) & 255;
      short8 a;
#pragma unroll
      for (int i = 0; i < 8; ++i) {
        int jj = quad * 8 + i;
        a[i] = (short)f2bf(kx[jj][d] * kx[jj][e]);   // chi: no 0.5 (psi carries it)
      }
      afr[mm] = a;
    }
    // B-fragments from V^T (bf16, direct 16B loads); MFMA
#pragma unroll
    for (int nt = 0; nt < 5; ++nt) {
      int ncol = nt * 16 + n16;
      short8 b = zero8();
      if (ncol < NZ) b = *(const short8*)(vtb + (size_t)ncol * LSEQ + jt * 32 + quad * 8);
      acc[0][nt] = __builtin_amdgcn_mfma_f32_16x16x32_bf16(afr[0], b, acc[0][nt], 0, 0, 0);
      acc[1][nt] = __builtin_amdgcn_mfma_f32_16x16x32_bf16(afr[1], b, acc[1][nt], 0, 0, 0);
    }
  }
  __syncthreads();
  // C-layout: row(feat-local) = quad*4+reg, col = n16
#pragma unroll
  for (int mm = 0; mm < 2; ++mm)
#pragma unroll
    for (int nt = 0; nt < 5; ++nt) {
      int col = nt * 16 + n16;
      if (col < NZ) {
#pragma unroll
        for (int r = 0; r < 4; ++r)
          tile[(w * 2 + mm) * 16 + quad * 4 + r][col] = acc[mm][nt][r];
      }
    }
  __syncthreads();
  unsigned short* stc = st + (size_t)(bh * NC + c) * NZ * NF;
  for (int i = t; i < NZ * NF; i += 320) {
    int n = i / NF, kk = i - n * NF;
    stc[i] = (unsigned short)f2bf(tile[kk][n]);
  }
}

// ---------------- pass_b: in-place exclusive prefix over chunks (bf16 io, fp32 run)
__global__ __launch_bounds__(256) void pass_b(unsigned short* __restrict__ st) {
  const int PER = NZ * NF;              // 10400
  const int TOT = BH * PER;             // 332800
  int idx = blockIdx.x * 256 + threadIdx.x;
  if (idx >= TOT) return;
  int bh = idx / PER, r = idx - bh * PER;
  unsigned short* p = st + (size_t)bh * NC * PER + r;
  float run = 0.f;
#pragma unroll
  for (int c = 0; c < NC; ++c) {
    unsigned short uv = p[(size_t)c * PER];
    float val = __uint_as_float(((unsigned)uv) << 16);
    p[(size_t)c * PER] = (unsigned short)f2bf(run);
    run += val;
  }
}

// ---------------- pass_c: O = (psi(Q)·S + causal phi(QK^T)·V') / z   (all MFMA)
// 512 blocks, 512 threads = 8 waves; wave w -> query M-tiles {2w,2w+1} (queries 32w..32w+31).
__global__ __launch_bounds__(512) void pass_c(const float* __restrict__ q,
                                              const unsigned short* __restrict__ kbf,
                                              const unsigned short* __restrict__ vt,
                                              const unsigned short* __restrict__ st,
                                              float* __restrict__ out) {
  __shared__ float qx[CS][18];
  __shared__ unsigned tbl[NF];
  __shared__ __align__(16) unsigned short ptile[8][32 * 40];
  __shared__ float zline[CS];
  int blk = blockIdx.x, bh = blk >> 4, c = blk & 15;
  const size_t base = (size_t)bh * LSEQ + (size_t)c * CS;
  const float* qc = q + base * D;
  int t = threadIdx.x, w = t >> 6, lane = t & 63, quad = lane >> 4, n16 = lane & 15;

  for (int i = t; i < CS * D; i += 512) {
    int row = i >> 4, dd = i & 15;
    qx[row][dd] = qc[i] * 0.25f;              // d^-0.5
  }
  for (int i = t; i < CS; i += 512) { qx[i][16] = 1.f; qx[i][17] = 0.f; }
  if (t < NF) tbl[t] = feat_tbl(t);
  __syncthreads();

  f32x4 acc[2][5];
#pragma unroll
  for (int mm = 0; mm < 2; ++mm)
#pragma unroll
    for (int nt = 0; nt < 5; ++nt) acc[mm][nt] = (f32x4){0.f, 0.f, 0.f, 0.f};

  // ---- inter: acc += psi(Q) · S_prefix
  const unsigned short* stc = st + (size_t)(bh * NC + c) * NZ * NF;
  for (int ks = 0; ks < KSTEPS; ++ks) {
    short8 afr[2];
#pragma unroll
    for (int mm = 0; mm < 2; ++mm) {
      int m = (w * 2 + mm) * 16 + n16;
      short8 a;
#pragma unroll
      for (int i = 0; i < 8; ++i) {
        int f = ks * 32 + quad * 8 + i;
        unsigned tv = tbl[f];
        float val = qx[m][tv & 255] * qx[m][(tv >> 8) & 255];
        if (tv & 0x10000u) val *= 0.5f;
        a[i] = (short)f2bf(val);
      }
      afr[mm] = a;
    }
#pragma unroll
    for (int nt = 0; nt < 5; ++nt) {
      int ncol = nt * 16 + n16;
      short8 b = zero8();
      if (ncol < NZ) b = *(const short8*)(stc + (size_t)ncol * NF + ks * 32 + quad * 8);
      acc[0][nt] = __builtin_amdgcn_mfma_f32_16x16x32_bf16(afr[0], b, acc[0][nt], 0, 0, 0);
      acc[1][nt] = __builtin_amdgcn_mfma_f32_16x16x32_bf16(afr[1], b, acc[1][nt], 0, 0, 0);
    }
  }

  // ---- intra: causal phi attention, j-tiles of 32 keys, jt <= w only
  short8 qfr[2];
#pragma unroll
  for (int mm = 0; mm < 2; ++mm) {
    int m = (w * 2 + mm) * 16 + n16;
    short8 a = zero8();
    if (quad < 2) {
#pragma unroll
      for (int i = 0; i < 8; ++i) a[i] = (short)f2bf(qx[m][quad * 8 + i]);
    }
    qfr[mm] = a;
  }
  const unsigned short* kbc = kbf + base * D;
  const unsigned short* vtb = vt + (size_t)bh * NZ * LSEQ + (size_t)c * CS;
  unsigned short* pw = &ptile[w][0];
  short8 ones;
#pragma unroll
  for (int i = 0; i < 8; ++i) ones[i] = (short)0x3F80;

  for (int jt = 0; jt <= w; ++jt) {
    // S = Q K^T  (K=16 padded to 32: quads 2,3 are zero on both sides)
    short8 kb[2];
#pragma unroll
    for (int ntk = 0; ntk < 2; ++ntk) {
      short8 b = zero8();
      if (quad < 2)
        b = *(const short8*)(kbc + (size_t)(jt * 32 + ntk * 16 + n16) * D + quad * 8);
      kb[ntk] = b;
    }
    f32x4 zf = (f32x4){0.f, 0.f, 0.f, 0.f};
    f32x4 s[2][2];
#pragma unroll
    for (int mm = 0; mm < 2; ++mm)
#pragma unroll
      for (int ntk = 0; ntk < 2; ++ntk)
        s[mm][ntk] = __builtin_amdgcn_mfma_f32_16x16x32_bf16(qfr[mm], kb[ntk], zf, 0, 0, 0);
    // phi + causal mask -> P tile (per-wave LDS, C-layout -> A-layout)
    bool diag = (jt == w);
#pragma unroll
    for (int mm = 0; mm < 2; ++mm)
#pragma unroll
      for (int ntk = 0; ntk < 2; ++ntk)
#pragma unroll
        for (int r = 0; r < 4; ++r) {
          float sv = s[mm][ntk][r];
          float phi = fmaf(0.5f * sv, sv, sv) + 1.0f;
          if (diag) {
            int qrow = mm * 16 + quad * 4 + r;
            int kcol = ntk * 16 + n16;
            if (kcol > qrow) phi = 0.f;
          }
          pw[(mm * 16 + quad * 4 + r) * 40 + ntk * 16 + n16] = (unsigned short)f2bf(phi);
        }
    // P·V' (z via ones column 64)
    short8 pa[2];
#pragma unroll
    for (int mm = 0; mm < 2; ++mm)
      pa[mm] = *(const short8*)(pw + (mm * 16 + n16) * 40 + quad * 8);
#pragma unroll
    for (int nt = 0; nt < 5; ++nt) {
      int ncol = nt * 16 + n16;
      short8 b;
      if (ncol < 64)      b = *(const short8*)(vtb + (size_t)ncol * LSEQ + jt * 32 + quad * 8);
      else if (ncol == 64) b = ones;
      else                 b = zero8();
      acc[0][nt] = __builtin_amdgcn_mfma_f32_16x16x32_bf16(pa[0], b, acc[0][nt], 0, 0, 0);
      acc[1][nt] = __builtin_amdgcn_mfma_f32_16x16x32_bf16(pa[1], b, acc[1][nt], 0, 0, 0);
    }
  }

  // ---- epilogue: z broadcast via per-wave LDS rows, normalize, store
  if (n16 == 0) {
#pragma unroll
    for (int mm = 0; mm < 2; ++mm)
#pragma unroll
      for (int r = 0; r < 4; ++r)
        zline[(w * 2 + mm) * 16 + quad * 4 + r] = acc[mm][4][r];
  }
  float* oc = out + base * DV;
#pragma unroll
  for (int mm = 0; mm < 2; ++mm)
#pragma unroll
    for (int r = 0; r < 4; ++r) {
      int qrow = (w * 2 + mm) * 16 + quad * 4 + r;
      float inv = 1.0f / (zline[qrow] + 1e-6f);
#pragma unroll
      for (int nt = 0; nt < 4; ++nt)
        oc[(size_t)qrow * DV + nt * 16 + n16] = acc[mm][nt][r] * inv;
    }
}

extern "C" void kernel_launch(void* const* d_in, const int* in_sizes, int n_in,
                              void* d_out, int out_size, void* d_ws, size_t ws_size,
                              hipStream_t stream) {
  (void)in_sizes; (void)n_in; (void)out_size; (void)ws_size;
  const float* q = (const float*)d_in[0];
  const float* k = (const float*)d_in[1];
  const float* v = (const float*)d_in[2];
  char* wsb = (char*)d_ws;
  unsigned*       kbf32 = (unsigned*)(wsb + OFF_KBF);
  unsigned short* kbf   = (unsigned short*)(wsb + OFF_KBF);
  unsigned short* vtp   = (unsigned short*)(wsb + OFF_VT);
  unsigned short* stp   = (unsigned short*)(wsb + OFF_ST);

  pass0_k<<<4096, 256, 0, stream>>>(k, kbf32);
  pass0_v<<<512, 256, 0, stream>>>(v, (unsigned*)vtp);
  pass_a<<<BH * NC, 320, 0, stream>>>(k, vtp, stp);
  pass_b<<<1300, 256, 0, stream>>>(stp);
  pass_c<<<BH * NC, 512, 0, stream>>>(q, kbf, vtp, stp, (float*)d_out);
}